// Round 6
// baseline (457.235 us; speedup 1.0000x reference)
//
#include <hip/hip_runtime.h>
#include <math.h>

#define NAG 10
#define PP  65536
#define EE  64
#define INW 16
#define TP  4              // p's per group (one wave each)
#define RR  (TP*NAG)       // 40 rows
#define SH  72             // bf16 LDS stride for row-major 64-wide tiles
#define SX  40             // bf16 LDS stride for X tile
#define SZT 52             // shorts stride per e-row of col-major Z^T
#define SU  68             // f32 stride for u output tile
#define NBLK 1536
#define NGRP (PP/TP)       // 16384

typedef __attribute__((ext_vector_type(8))) short short8;
typedef __attribute__((ext_vector_type(4))) short short4v;
typedef __attribute__((ext_vector_type(4))) float f32x4;

__device__ __forceinline__ short f2bf(float x){
    unsigned u = __float_as_uint(x);
    return (short)((u + 0x8000u) >> 16);     // round-nearest (ties away)
}
__device__ __forceinline__ float bf2f(short s){
    return __uint_as_float(((unsigned)(unsigned short)s) << 16);
}
__device__ __forceinline__ unsigned pack2(float a, float b){
    return (unsigned)(unsigned short)f2bf(a) | ((unsigned)(unsigned short)f2bf(b) << 16);
}

__global__ __launch_bounds__(256, 6) void mpnn_mfma5(
    const float* __restrict__ inp,
    const float* __restrict__ W_enc, const float* __restrict__ b_enc,
    const float* __restrict__ W_goal, const float* __restrict__ b_goal,
    const float* __restrict__ Wq, const float* __restrict__ Wk,
    const float* __restrict__ Wv, const float* __restrict__ Wo,
    const float* __restrict__ W_upd, const float* __restrict__ b_upd,
    float* __restrict__ out)
{
    // pool: [hs 6912][gsb 6912][zsbT 6656] = 20480 B
    //  - init overlay:   Wf (64x64 f32 = 16384 B) at pool base
    //  - gsb holds G, then m' (row-major, same stride)
    //  - epilog overlay: outt_u (40*SU*4 = 10880 B) + outt_h (2048 B) over gsb+zsbT
    __shared__ __align__(16) char pool[20480];
    __shared__ __align__(16) short Xs[48 * SX];
    __shared__ float goal_s[TP][2];

    short* const hs   = (short*)pool;
    short* const gsb  = hs  + 48*SH;
    short* const zsbT = gsb + 48*SH;
    float* const Wf     = (float*)pool;
    float* const outt_u = (float*)gsb;
    float* const outt_h = outt_u + RR*SU;

    const int tid  = threadIdx.x;
    const int w    = tid >> 6;      // wave id == col-tile == p_local for attention
    const int l    = tid & 63;
    const int lrow = l & 15;
    const int lk   = l >> 4;
    const int col  = 16*w + lrow;

    // ---- zero X once (cols beyond data and rows 40..47 stay zero forever)
    for (int i = tid; i < 48*SX; i += 256) Xs[i] = 0;

    // ---- init 1: Wqk = (Wq @ Wk^T) * scale   (fp32, in LDS)
    for (int i = tid; i < EE*EE; i += 256) {
        const int r = i >> 6, c = i & 63;
        float s = 0.f;
        #pragma unroll 8
        for (int t = 0; t < EE; ++t)
            s = fmaf(Wq[r*EE + t], Wk[c*EE + t], s);
        Wf[i] = s * 0.125f;
    }
    __syncthreads();

    short8 fqk[2];
    #pragma unroll
    for (int ks = 0; ks < 2; ++ks)
        #pragma unroll
        for (int j = 0; j < 8; ++j)
            fqk[ks][j] = f2bf(Wf[(32*ks + lk*8 + j)*EE + col]);
    __syncthreads();

    // ---- init 2: Wc = Wo @ W_upd[64:128]  (fp32, in LDS)
    for (int i = tid; i < EE*EE; i += 256) {
        const int r = i >> 6, c = i & 63;
        float s = 0.f;
        #pragma unroll 8
        for (int d = 0; d < EE; ++d)
            s = fmaf(Wo[r*EE + d], W_upd[(EE + d)*EE + c], s);
        Wf[i] = s;
    }
    __syncthreads();

    // ---- init 3: fvc frags of Wvc = Wv @ Wc  (per-lane dots; Wc stays in LDS)
    short8 fvc[2];
    #pragma unroll
    for (int ks = 0; ks < 2; ++ks)
        #pragma unroll
        for (int j = 0; j < 8; ++j) {
            const int k = 32*ks + lk*8 + j;
            float s = 0.f;
            #pragma unroll 8
            for (int d = 0; d < EE; ++d)
                s = fmaf(Wv[k*EE + d], Wf[d*EE + col], s);
            fvc[ks][j] = f2bf(s);
        }

    // ---- remaining B-frags straight from global
    short8 fenc, fuw[2];
    #pragma unroll
    for (int j = 0; j < 8; ++j) {
        int k = lk*8 + j;
        fenc[j] = (k < 14) ? f2bf(W_enc[k*EE + col]) : (short)0;
    }
    #pragma unroll
    for (int ks = 0; ks < 2; ++ks)
        #pragma unroll
        for (int j = 0; j < 8; ++j)
            fuw[ks][j] = f2bf(W_upd[(32*ks + lk*8 + j)*EE + col]);
    const float bencv = b_enc[col];
    const float bupdv = b_upd[col];
    const float wg0 = W_goal[l], wg1 = W_goal[EE + l], bg = b_goal[l];

    // ---- input staging lanes: lane -> one float4 (row r_=pl*NAG+a, quarter q_)
    const bool hasx = tid < RR*4;
    const int  r_ = tid >> 2, q_ = tid & 3;
    const int  pl_ = r_ / NAG, a_ = r_ - pl_*NAG;
    const size_t xbase = (size_t)a_*PP*INW + (size_t)pl_*INW + (size_t)q_*4;
    f32x4 xin = {0.f,0.f,0.f,0.f};
    if (hasx) xin = *(const f32x4*)(inp + xbase + (size_t)blockIdx.x * (TP*INW));

    // ---- prologue stage of group g0 = blockIdx.x
    if (hasx) {
        uint2 pk = { pack2(xin[0], xin[1]), pack2(xin[2], xin[3]) };
        *(uint2*)&Xs[r_*SX + q_*4] = pk;   // goal lands in X cols 14,15: fenc is 0 there
        if (q_ == 3 && a_ == 0) { goal_s[pl_][0] = xin[2]; goal_s[pl_][1] = xin[3]; }
        if ((int)blockIdx.x + NBLK < NGRP)
            xin = *(const f32x4*)(inp + xbase + (size_t)(blockIdx.x + NBLK) * (TP*INW));
    }
    __syncthreads();   // init reads + stage writes done

    for (int g = blockIdx.x; g < NGRP; g += NBLK) {
        const int p0 = g * TP;

        // leader h2 (goal_s staged for this g; overwritten only at this iter's attn stage)
        const float h2l = fmaxf(fmaf(goal_s[w][0], wg0,
                           fmaf(goal_s[w][1], wg1, bg)), 0.f);

        // ---- encoder: h = relu(X @ W_enc + b_enc)
        #pragma unroll
        for (int rt = 0; rt < 3; ++rt) {
            const short8 ax = *reinterpret_cast<const short8*>(&Xs[(16*rt + lrow)*SX + lk*8]);
            f32x4 acc = {0.f,0.f,0.f,0.f};
            acc = __builtin_amdgcn_mfma_f32_16x16x32_bf16(ax, fenc, acc, 0,0,0);
            #pragma unroll
            for (int j = 0; j < 4; ++j)
                hs[(16*rt + lk*4 + j)*SH + col] = f2bf(fmaxf(acc[j] + bencv, 0.f));
        }
        __syncthreads();   // C

        // ---- G = h @ Wqk (row-major), Z = h @ Wvc (col-major zsbT)
        #pragma unroll
        for (int rt = 0; rt < 3; ++rt) {
            const short8 a0 = *reinterpret_cast<const short8*>(&hs[(16*rt + lrow)*SH + lk*8]);
            const short8 a1 = *reinterpret_cast<const short8*>(&hs[(16*rt + lrow)*SH + 32 + lk*8]);
            f32x4 ga = {0.f,0.f,0.f,0.f}, za = {0.f,0.f,0.f,0.f};
            ga = __builtin_amdgcn_mfma_f32_16x16x32_bf16(a0, fqk[0], ga, 0,0,0);
            ga = __builtin_amdgcn_mfma_f32_16x16x32_bf16(a1, fqk[1], ga, 0,0,0);
            za = __builtin_amdgcn_mfma_f32_16x16x32_bf16(a0, fvc[0], za, 0,0,0);
            za = __builtin_amdgcn_mfma_f32_16x16x32_bf16(a1, fvc[1], za, 0,0,0);
            #pragma unroll
            for (int j = 0; j < 4; ++j)
                gsb[(16*rt + lk*4 + j)*SH + col] = f2bf(ga[j]);
            uint2 zpk = { pack2(za[0], za[1]), pack2(za[2], za[3]) };
            *(uint2*)&zsbT[col*SZT + 16*rt + lk*4] = zpk;
        }
        const float h0 = bf2f(hs[(w*NAG)*SH + l]);   // agent-0 h, elem l, p=p0+w
        __syncthreads();   // D

        // ---- attention for p = w: S^T = h @ G^T (per-wave), softmax in-register,
        //      m' = P @ Z written row-major into dead G rows
        {
            const int r0 = w * NAG;
            const short8 aH0 = *reinterpret_cast<const short8*>(&hs [(r0+lrow)*SH + lk*8]);
            const short8 aH1 = *reinterpret_cast<const short8*>(&hs [(r0+lrow)*SH + 32 + lk*8]);
            const short8 aG0 = *reinterpret_cast<const short8*>(&gsb[(r0+lrow)*SH + lk*8]);
            const short8 aG1 = *reinterpret_cast<const short8*>(&gsb[(r0+lrow)*SH + 32 + lk*8]);
            f32x4 st = {0.f,0.f,0.f,0.f};
            st = __builtin_amdgcn_mfma_f32_16x16x32_bf16(aH0, aG0, st, 0,0,0);
            st = __builtin_amdgcn_mfma_f32_16x16x32_bf16(aH1, aG1, st, 0,0,0);
            // lane holds S[q=lrow][k=lk*4+j] (scale already folded into Wqk)
            const int q = lrow;
            float c[4]; float mx4 = -1e30f;
            #pragma unroll
            for (int j = 0; j < 4; ++j) {
                const int k = lk*4 + j;
                const bool valid = (q < NAG) && (k < NAG) && (k != q) && (k != 0);
                c[j] = valid ? st[j] : -1e30f;
                mx4 = fmaxf(mx4, c[j]);
            }
            float mx = fmaxf(mx4, __shfl_xor(mx4, 16, 64));
            mx = fmaxf(mx, __shfl_xor(mx, 32, 64));
            float e[4], s4 = 0.f;
            #pragma unroll
            for (int j = 0; j < 4; ++j) { e[j] = __expf(c[j] - mx); s4 += e[j]; }
            float s = s4;
            s += __shfl_xor(s, 16, 64);
            s += __shfl_xor(s, 32, 64);
            const float inv = 1.f / s;

            short4v pa;
            #pragma unroll
            for (int j = 0; j < 4; ++j) pa[j] = f2bf(e[j] * inv);
            #pragma unroll
            for (int t = 0; t < 4; ++t) {
                const short* vp = &zsbT[(16*t + lrow)*SZT + r0 + lk*4];
                const unsigned lo = *(const unsigned*)(vp);
                const unsigned hi = *(const unsigned*)(vp + 2);
                short4v vb;
                vb[0] = (short)(lo & 0xffff); vb[1] = (short)(lo >> 16);
                vb[2] = (short)(hi & 0xffff); vb[3] = (short)(hi >> 16);
                f32x4 md = {0.f,0.f,0.f,0.f};
                md = __builtin_amdgcn_mfma_f32_16x16x16bf16_1k(pa, vb, md, 0,0,0);
                // lane holds m'[a=lk*4+j][e=16t+lrow]
                #pragma unroll
                for (int j = 0; j < 4; ++j) {
                    const int a = lk*4 + j;
                    if (a < NAG) gsb[(r0+a)*SH + 16*t + lrow] = f2bf(md[j]);
                }
            }
        }
        // ---- stage NEXT group's X/goal (ordered vs next enc by barriers G..C)
        if (hasx && g + NBLK < NGRP) {
            uint2 pk = { pack2(xin[0], xin[1]), pack2(xin[2], xin[3]) };
            *(uint2*)&Xs[r_*SX + q_*4] = pk;
            if (q_ == 3 && a_ == 0) { goal_s[pl_][0] = xin[2]; goal_s[pl_][1] = xin[3]; }
            if (g + 2*NBLK < NGRP)
                xin = *(const f32x4*)(inp + xbase + (size_t)(g + 2*NBLK) * (TP*INW));
        }
        __syncthreads();   // G

        // ---- u = relu(h @ Wu_top + m' + b_upd)
        f32x4 uacc[3];
        #pragma unroll
        for (int rt = 0; rt < 3; ++rt) {
            const short8 a0 = *reinterpret_cast<const short8*>(&hs[(16*rt + lrow)*SH + lk*8]);
            const short8 a1 = *reinterpret_cast<const short8*>(&hs[(16*rt + lrow)*SH + 32 + lk*8]);
            f32x4 ua = {0.f,0.f,0.f,0.f};
            ua = __builtin_amdgcn_mfma_f32_16x16x32_bf16(a0, fuw[0], ua, 0,0,0);
            ua = __builtin_amdgcn_mfma_f32_16x16x32_bf16(a1, fuw[1], ua, 0,0,0);
            #pragma unroll
            for (int j = 0; j < 4; ++j)
                ua[j] += bf2f(gsb[(16*rt + lk*4 + j)*SH + col]);   // + m'
            uacc[rt] = ua;
        }
        __syncthreads();   // H: all gsb/zsbT reads done -> overlay outt

        // ---- build fp32 output tile in LDS
        #pragma unroll
        for (int rt = 0; rt < 3; ++rt) {
            #pragma unroll
            for (int j = 0; j < 4; ++j) {
                const int r = 16*rt + lk*4 + j;
                if (r < RR) outt_u[r*SU + col] = fmaxf(uacc[rt][j] + bupdv, 0.f);
            }
        }
        outt_h[(w*2 + 0)*64 + l] = h2l;
        outt_h[(w*2 + 1)*64 + l] = h0;
        __syncthreads();   // I

        // ---- coalesced full-line nontemporal stores: 1024 B / wave-instr
        float* __restrict__ outF = out + (size_t)PP*128;
        #pragma unroll
        for (int it = 0; it < 5; ++it) {
            const int flat   = it*256 + tid;
            const int a      = flat >> 7;
            const int within = flat & 127;
            const int pl     = within >> 5;
            const int j4     = within & 31;
            const float* src = (j4 < 16)
                ? &outt_u[(pl*NAG + a)*SU + j4*4]
                : &outt_h[(pl*2 + (a == 0 ? 0 : 1))*64 + (j4 - 16)*4];
            const f32x4 v = *reinterpret_cast<const f32x4*>(src);
            float* dst = (a == 0)
                ? (out  + ((size_t)(p0 + pl))*128 + j4*4)
                : (outF + ((size_t)(a-1)*PP + (size_t)(p0 + pl))*128 + j4*4);
            __builtin_nontemporal_store(v, (f32x4*)dst);
        }
        __syncthreads();   // A': outt reads done before next enc writes... (cheap safety)
    }
}

extern "C" void kernel_launch(void* const* d_in, const int* in_sizes, int n_in,
                              void* d_out, int out_size, void* d_ws, size_t ws_size,
                              hipStream_t stream) {
    const float* inp    = (const float*)d_in[0];
    const float* W_enc  = (const float*)d_in[1];
    const float* b_enc  = (const float*)d_in[2];
    const float* W_goal = (const float*)d_in[3];
    const float* b_goal = (const float*)d_in[4];
    const float* Wq     = (const float*)d_in[5];
    const float* Wk     = (const float*)d_in[6];
    const float* Wv     = (const float*)d_in[7];
    const float* Wo     = (const float*)d_in[8];
    const float* W_upd  = (const float*)d_in[9];
    const float* b_upd  = (const float*)d_in[10];

    hipLaunchKernelGGL(mpnn_mfma5, dim3(NBLK), dim3(256), 0, stream,
                       inp, W_enc, b_enc, W_goal, b_goal,
                       Wq, Wk, Wv, Wo, W_upd, b_upd, (float*)d_out);
}

// Round 7
// 303.968 us; speedup vs baseline: 1.5042x; 1.5042x over previous
//
#include <hip/hip_runtime.h>
#include <math.h>

#define NAG 10
#define PP  65536
#define EE  64
#define INW 16
#define TP  4              // p's per group (one wave each)
#define RR  (TP*NAG)       // 40 rows
#define SH  72             // bf16 LDS stride for row-major 64-wide tiles
#define SX  40             // bf16 LDS stride for X tile
#define SZT 52             // shorts stride per e-row of col-major Z^T
#define SU  68             // f32 stride for u output tile
#define NBLK 1536
#define NGRP (PP/TP)       // 16384

typedef __attribute__((ext_vector_type(8))) short short8;
typedef __attribute__((ext_vector_type(4))) short short4v;
typedef __attribute__((ext_vector_type(4))) float f32x4;

__device__ __forceinline__ short f2bf(float x){
    unsigned u = __float_as_uint(x);
    return (short)((u + 0x8000u) >> 16);     // round-nearest (ties away)
}
__device__ __forceinline__ float bf2f(short s){
    return __uint_as_float(((unsigned)(unsigned short)s) << 16);
}
__device__ __forceinline__ unsigned pack2(float a, float b){
    return (unsigned)(unsigned short)f2bf(a) | ((unsigned)(unsigned short)f2bf(b) << 16);
}

__global__ __launch_bounds__(256, 6) void mpnn_mfma6(
    const float* __restrict__ inp,
    const float* __restrict__ W_enc, const float* __restrict__ b_enc,
    const float* __restrict__ W_goal, const float* __restrict__ b_goal,
    const float* __restrict__ Wq, const float* __restrict__ Wk,
    const float* __restrict__ Wv, const float* __restrict__ Wo,
    const float* __restrict__ W_upd, const float* __restrict__ b_upd,
    float* __restrict__ out)
{
    // pool: [hs 6912][gsb 6912][zsbT 6656] = 20480 B
    //  - init overlay 1: WkT (64x65 f32 = 16640 B)  [transposed Wk staging]
    //  - init overlay 2: Wc  (64x64 f32 = 16384 B)
    //  - epilog overlay: outt_u (40*SU*4) + outt_h (2048 B) over gsb+zsbT
    __shared__ __align__(16) char pool[20480];
    __shared__ __align__(16) short Xs[48 * SX];
    __shared__ float goal_s[TP][2];

    short* const hs   = (short*)pool;
    short* const gsb  = hs  + 48*SH;
    short* const zsbT = gsb + 48*SH;
    float* const WkT    = (float*)pool;        // [t][r] = Wk[r][t], stride 65
    float* const Wc     = (float*)pool;
    float* const outt_u = (float*)gsb;
    float* const outt_h = outt_u + RR*SU;

    const int tid  = threadIdx.x;
    const int w    = tid >> 6;      // wave id == col-tile == p_local for attention
    const int l    = tid & 63;
    const int lrow = l & 15;
    const int lk   = l >> 4;
    const int col  = 16*w + lrow;

    // ---- zero X once (cols beyond data and rows 40..47 stay zero forever)
    for (int i = tid; i < 48*SX; i += 256) Xs[i] = 0;

    // ---- init 1a: stage Wk transposed (coalesced read; padded conflict-free write)
    for (int i = tid; i < EE*EE; i += 256) {
        const int r = i >> 6, t = i & 63;
        WkT[t*65 + r] = Wk[i];
    }
    __syncthreads();

    // ---- init 1b: fqk frags of Wqk = (Wq @ Wk^T)*scale, per-lane dots
    //      Wq reads: 4 distinct rows/wave (broadcast); WkT reads: 16 consecutive banks (free)
    short8 fqk[2];
    #pragma unroll
    for (int ks = 0; ks < 2; ++ks)
        #pragma unroll
        for (int j = 0; j < 8; ++j) {
            const int k = 32*ks + lk*8 + j;
            float s = 0.f;
            #pragma unroll 8
            for (int t = 0; t < EE; ++t)
                s = fmaf(Wq[k*EE + t], WkT[t*65 + col], s);
            fqk[ks][j] = f2bf(s * 0.125f);
        }
    __syncthreads();   // WkT reads done -> pool reusable

    // ---- init 2: Wc = Wo @ W_upd[64:128]  (coalesced: n per-lane consecutive)
    for (int i = tid; i < EE*EE; i += 256) {
        const int r = i >> 6, c = i & 63;
        float s = 0.f;
        #pragma unroll 8
        for (int d = 0; d < EE; ++d)
            s = fmaf(Wo[r*EE + d], W_upd[(EE + d)*EE + c], s);
        Wc[i] = s;
    }
    __syncthreads();

    // ---- init 3: fvc frags of Wvc = Wv @ Wc (Wv rows broadcast; Wc LDS reads free)
    short8 fvc[2];
    #pragma unroll
    for (int ks = 0; ks < 2; ++ks)
        #pragma unroll
        for (int j = 0; j < 8; ++j) {
            const int k = 32*ks + lk*8 + j;
            float s = 0.f;
            #pragma unroll 8
            for (int d = 0; d < EE; ++d)
                s = fmaf(Wv[k*EE + d], Wc[d*EE + col], s);
            fvc[ks][j] = f2bf(s);
        }

    // ---- remaining B-frags straight from global
    short8 fenc, fuw[2];
    #pragma unroll
    for (int j = 0; j < 8; ++j) {
        int k = lk*8 + j;
        fenc[j] = (k < 14) ? f2bf(W_enc[k*EE + col]) : (short)0;
    }
    #pragma unroll
    for (int ks = 0; ks < 2; ++ks)
        #pragma unroll
        for (int j = 0; j < 8; ++j)
            fuw[ks][j] = f2bf(W_upd[(32*ks + lk*8 + j)*EE + col]);
    const float bencv = b_enc[col];
    const float bupdv = b_upd[col];
    const float wg0 = W_goal[l], wg1 = W_goal[EE + l], bg = b_goal[l];

    // ---- input staging lanes: lane -> one float4 (row r_=pl*NAG+a, quarter q_)
    const bool hasx = tid < RR*4;
    const int  r_ = tid >> 2, q_ = tid & 3;
    const int  pl_ = r_ / NAG, a_ = r_ - pl_*NAG;
    const size_t xbase = (size_t)a_*PP*INW + (size_t)pl_*INW + (size_t)q_*4;
    f32x4 xin = {0.f,0.f,0.f,0.f};
    if (hasx) xin = *(const f32x4*)(inp + xbase + (size_t)blockIdx.x * (TP*INW));

    // ---- prologue stage of group g0 = blockIdx.x
    if (hasx) {
        uint2 pk = { pack2(xin[0], xin[1]), pack2(xin[2], xin[3]) };
        *(uint2*)&Xs[r_*SX + q_*4] = pk;   // goal lands in X cols 14,15: fenc is 0 there
        if (q_ == 3 && a_ == 0) { goal_s[pl_][0] = xin[2]; goal_s[pl_][1] = xin[3]; }
        if ((int)blockIdx.x + NBLK < NGRP)
            xin = *(const f32x4*)(inp + xbase + (size_t)(blockIdx.x + NBLK) * (TP*INW));
    }
    __syncthreads();   // init-3 reads + stage writes done

    for (int g = blockIdx.x; g < NGRP; g += NBLK) {
        const int p0 = g * TP;

        // leader h2 (goal_s staged for this g; overwritten only at this iter's attn stage)
        const float h2l = fmaxf(fmaf(goal_s[w][0], wg0,
                           fmaf(goal_s[w][1], wg1, bg)), 0.f);

        // ---- encoder: h = relu(X @ W_enc + b_enc)
        #pragma unroll
        for (int rt = 0; rt < 3; ++rt) {
            const short8 ax = *reinterpret_cast<const short8*>(&Xs[(16*rt + lrow)*SX + lk*8]);
            f32x4 acc = {0.f,0.f,0.f,0.f};
            acc = __builtin_amdgcn_mfma_f32_16x16x32_bf16(ax, fenc, acc, 0,0,0);
            #pragma unroll
            for (int j = 0; j < 4; ++j)
                hs[(16*rt + lk*4 + j)*SH + col] = f2bf(fmaxf(acc[j] + bencv, 0.f));
        }
        __syncthreads();   // C  (also orders prev-iter outt reads vs this GZ's gsb writes)

        // ---- G = h @ Wqk (row-major), Z = h @ Wvc (col-major zsbT)
        #pragma unroll
        for (int rt = 0; rt < 3; ++rt) {
            const short8 a0 = *reinterpret_cast<const short8*>(&hs[(16*rt + lrow)*SH + lk*8]);
            const short8 a1 = *reinterpret_cast<const short8*>(&hs[(16*rt + lrow)*SH + 32 + lk*8]);
            f32x4 ga = {0.f,0.f,0.f,0.f}, za = {0.f,0.f,0.f,0.f};
            ga = __builtin_amdgcn_mfma_f32_16x16x32_bf16(a0, fqk[0], ga, 0,0,0);
            ga = __builtin_amdgcn_mfma_f32_16x16x32_bf16(a1, fqk[1], ga, 0,0,0);
            za = __builtin_amdgcn_mfma_f32_16x16x32_bf16(a0, fvc[0], za, 0,0,0);
            za = __builtin_amdgcn_mfma_f32_16x16x32_bf16(a1, fvc[1], za, 0,0,0);
            #pragma unroll
            for (int j = 0; j < 4; ++j)
                gsb[(16*rt + lk*4 + j)*SH + col] = f2bf(ga[j]);
            uint2 zpk = { pack2(za[0], za[1]), pack2(za[2], za[3]) };
            *(uint2*)&zsbT[col*SZT + 16*rt + lk*4] = zpk;
        }
        const float h0 = bf2f(hs[(w*NAG)*SH + l]);   // agent-0 h, elem l, p=p0+w
        __syncthreads();   // D

        // ---- attention for p = w: S^T = h @ G^T, in-register softmax, m' = P @ Z
        {
            const int r0 = w * NAG;
            const short8 aH0 = *reinterpret_cast<const short8*>(&hs [(r0+lrow)*SH + lk*8]);
            const short8 aH1 = *reinterpret_cast<const short8*>(&hs [(r0+lrow)*SH + 32 + lk*8]);
            const short8 aG0 = *reinterpret_cast<const short8*>(&gsb[(r0+lrow)*SH + lk*8]);
            const short8 aG1 = *reinterpret_cast<const short8*>(&gsb[(r0+lrow)*SH + 32 + lk*8]);
            f32x4 st = {0.f,0.f,0.f,0.f};
            st = __builtin_amdgcn_mfma_f32_16x16x32_bf16(aH0, aG0, st, 0,0,0);
            st = __builtin_amdgcn_mfma_f32_16x16x32_bf16(aH1, aG1, st, 0,0,0);
            // lane holds S[q=lrow][k=lk*4+j] (scale folded into Wqk)
            const int q = lrow;
            float c[4]; float mx4 = -1e30f;
            #pragma unroll
            for (int j = 0; j < 4; ++j) {
                const int k = lk*4 + j;
                const bool valid = (q < NAG) && (k < NAG) && (k != q) && (k != 0);
                c[j] = valid ? st[j] : -1e30f;
                mx4 = fmaxf(mx4, c[j]);
            }
            float mx = fmaxf(mx4, __shfl_xor(mx4, 16, 64));
            mx = fmaxf(mx, __shfl_xor(mx, 32, 64));
            float e[4], s4 = 0.f;
            #pragma unroll
            for (int j = 0; j < 4; ++j) { e[j] = __expf(c[j] - mx); s4 += e[j]; }
            float s = s4;
            s += __shfl_xor(s, 16, 64);
            s += __shfl_xor(s, 32, 64);
            const float inv = 1.f / s;

            short4v pa;
            #pragma unroll
            for (int j = 0; j < 4; ++j) pa[j] = f2bf(e[j] * inv);
            #pragma unroll
            for (int t = 0; t < 4; ++t) {
                const short* vp = &zsbT[(16*t + lrow)*SZT + r0 + lk*4];
                const unsigned lo = *(const unsigned*)(vp);
                const unsigned hi = *(const unsigned*)(vp + 2);
                short4v vb;
                vb[0] = (short)(lo & 0xffff); vb[1] = (short)(lo >> 16);
                vb[2] = (short)(hi & 0xffff); vb[3] = (short)(hi >> 16);
                f32x4 md = {0.f,0.f,0.f,0.f};
                md = __builtin_amdgcn_mfma_f32_16x16x16bf16_1k(pa, vb, md, 0,0,0);
                // lane holds m'[a=lk*4+j][e=16t+lrow]
                #pragma unroll
                for (int j = 0; j < 4; ++j) {
                    const int a = lk*4 + j;
                    if (a < NAG) gsb[(r0+a)*SH + 16*t + lrow] = f2bf(md[j]);
                }
            }
        }
        // ---- stage NEXT group's X/goal (ordered vs next enc by barriers G..C)
        if (hasx && g + NBLK < NGRP) {
            uint2 pk = { pack2(xin[0], xin[1]), pack2(xin[2], xin[3]) };
            *(uint2*)&Xs[r_*SX + q_*4] = pk;
            if (q_ == 3 && a_ == 0) { goal_s[pl_][0] = xin[2]; goal_s[pl_][1] = xin[3]; }
            if (g + 2*NBLK < NGRP)
                xin = *(const f32x4*)(inp + xbase + (size_t)(g + 2*NBLK) * (TP*INW));
        }
        __syncthreads();   // G

        // ---- u = relu(h @ Wu_top + m' + b_upd)
        f32x4 uacc[3];
        #pragma unroll
        for (int rt = 0; rt < 3; ++rt) {
            const short8 a0 = *reinterpret_cast<const short8*>(&hs[(16*rt + lrow)*SH + lk*8]);
            const short8 a1 = *reinterpret_cast<const short8*>(&hs[(16*rt + lrow)*SH + 32 + lk*8]);
            f32x4 ua = {0.f,0.f,0.f,0.f};
            ua = __builtin_amdgcn_mfma_f32_16x16x32_bf16(a0, fuw[0], ua, 0,0,0);
            ua = __builtin_amdgcn_mfma_f32_16x16x32_bf16(a1, fuw[1], ua, 0,0,0);
            #pragma unroll
            for (int j = 0; j < 4; ++j)
                ua[j] += bf2f(gsb[(16*rt + lk*4 + j)*SH + col]);   // + m'
            uacc[rt] = ua;
        }
        __syncthreads();   // H: all gsb/zsbT reads done -> overlay outt

        // ---- build fp32 output tile in LDS
        #pragma unroll
        for (int rt = 0; rt < 3; ++rt) {
            #pragma unroll
            for (int j = 0; j < 4; ++j) {
                const int r = 16*rt + lk*4 + j;
                if (r < RR) outt_u[r*SU + col] = fmaxf(uacc[rt][j] + bupdv, 0.f);
            }
        }
        outt_h[(w*2 + 0)*64 + l] = h2l;
        outt_h[(w*2 + 1)*64 + l] = h0;
        __syncthreads();   // I

        // ---- coalesced full-line nontemporal stores: 1024 B / wave-instr
        float* __restrict__ outF = out + (size_t)PP*128;
        #pragma unroll
        for (int it = 0; it < 5; ++it) {
            const int flat   = it*256 + tid;
            const int a      = flat >> 7;
            const int within = flat & 127;
            const int pl     = within >> 5;
            const int j4     = within & 31;
            const float* src = (j4 < 16)
                ? &outt_u[(pl*NAG + a)*SU + j4*4]
                : &outt_h[(pl*2 + (a == 0 ? 0 : 1))*64 + (j4 - 16)*4];
            const f32x4 v = *reinterpret_cast<const f32x4*>(src);
            float* dst = (a == 0)
                ? (out  + ((size_t)(p0 + pl))*128 + j4*4)
                : (outF + ((size_t)(a-1)*PP + (size_t)(p0 + pl))*128 + j4*4);
            __builtin_nontemporal_store(v, (f32x4*)dst);
        }
        // no trailing barrier: store reads (outt over gsb/zsbT) are ordered vs
        // next iteration's gsb/zsbT writes by barrier C; hs/Xs untouched here.
    }
}

extern "C" void kernel_launch(void* const* d_in, const int* in_sizes, int n_in,
                              void* d_out, int out_size, void* d_ws, size_t ws_size,
                              hipStream_t stream) {
    const float* inp    = (const float*)d_in[0];
    const float* W_enc  = (const float*)d_in[1];
    const float* b_enc  = (const float*)d_in[2];
    const float* W_goal = (const float*)d_in[3];
    const float* b_goal = (const float*)d_in[4];
    const float* Wq     = (const float*)d_in[5];
    const float* Wk     = (const float*)d_in[6];
    const float* Wv     = (const float*)d_in[7];
    const float* Wo     = (const float*)d_in[8];
    const float* W_upd  = (const float*)d_in[9];
    const float* b_upd  = (const float*)d_in[10];

    hipLaunchKernelGGL(mpnn_mfma6, dim3(NBLK), dim3(256), 0, stream,
                       inp, W_enc, b_enc, W_goal, b_goal,
                       Wq, Wk, Wv, Wo, W_upd, b_upd, (float*)d_out);
}